// Round 1
// baseline (1789.179 us; speedup 1.0000x reference)
//
#include <hip/hip_runtime.h>
#include <hip/hip_bf16.h>
#include <math.h>

#define N_NODES 100000
#define N_EDGES 800000
#define IN_C 96
#define OUT_C 64

// ---------------- degree / normalization ----------------

__global__ void deg_init_kernel(float* __restrict__ deg, int n) {
    int i = blockIdx.x * blockDim.x + threadIdx.x;
    if (i < n) deg[i] = 1.0f;  // self-loop contributes 1 to every node's degree
}

__global__ void deg_scatter_kernel(const int* __restrict__ col, float* __restrict__ deg, int e) {
    int i = blockIdx.x * blockDim.x + threadIdx.x;
    if (i < e) atomicAdd(&deg[col[i]], 1.0f);
}

__global__ void dinv_kernel(float* __restrict__ deg, int n) {
    int i = blockIdx.x * blockDim.x + threadIdx.x;
    if (i < n) {
        float d = deg[i];
        deg[i] = (d > 0.0f) ? rsqrtf(d) : 0.0f;
    }
}

__global__ void norm_kernel(const int* __restrict__ row, const int* __restrict__ col,
                            const float* __restrict__ dinv, float* __restrict__ norm, int e) {
    int i = blockIdx.x * blockDim.x + threadIdx.x;
    if (i < e) norm[i] = dinv[row[i]] * dinv[col[i]];
}

// ---------------- linear: y0 = x @ W^T (no bias) ----------------
// block: 256 threads = 4 nodes x 64 outputs. W transposed in LDS (stride-1 over o).

__global__ void linear_kernel(const float* __restrict__ x, const float* __restrict__ W,
                              float* __restrict__ y, int n) {
    __shared__ float Wt[IN_C * OUT_C];   // Wt[c*64 + o] = W[o*96 + c]  (24 KB)
    __shared__ float xs[4][IN_C];        // 1.5 KB

    for (int i = threadIdx.x; i < IN_C * OUT_C; i += 256) {
        int o = i / IN_C;
        int c = i - o * IN_C;
        Wt[c * OUT_C + o] = W[i];
    }
    int node0 = blockIdx.x * 4;
    for (int i = threadIdx.x; i < 4 * IN_C; i += 256) {
        int nl = i / IN_C;
        int c = i - nl * IN_C;
        int node = node0 + nl;
        xs[nl][c] = (node < n) ? x[(size_t)node * IN_C + c] : 0.0f;
    }
    __syncthreads();

    int nl = threadIdx.x >> 6;       // 0..3
    int o = threadIdx.x & 63;        // 0..63
    int node = node0 + nl;
    if (node >= n) return;

    float acc = 0.0f;
#pragma unroll
    for (int c = 0; c < IN_C; ++c) {
        acc += xs[nl][c] * Wt[c * OUT_C + o];
    }
    y[(size_t)node * OUT_C + o] = acc;
}

// ---------------- propagation hop (64 channels) ----------------
// dst[n] = dinv[n]^2 * src[n]   (self-loop, direct write)

__global__ void hop_init_kernel(const float* __restrict__ src, float* __restrict__ dst,
                                const float* __restrict__ dinv, int n) {
    int i = blockIdx.x * blockDim.x + threadIdx.x;   // i over n*16 float4 chunks
    int total = n * (OUT_C / 4);
    if (i >= total) return;
    int node = i >> 4;                                // /16
    float s = dinv[node];
    s = s * s;
    float4 v = reinterpret_cast<const float4*>(src)[i];
    v.x *= s; v.y *= s; v.z *= s; v.w *= s;
    reinterpret_cast<float4*>(dst)[i] = v;
}

// dst[col[e]] += norm[e] * src[row[e]]  (scatter, 16 float4 chunks per edge)

__global__ void hop_scatter_kernel(const float* __restrict__ src, float* __restrict__ dst,
                                   const int* __restrict__ row, const int* __restrict__ col,
                                   const float* __restrict__ norm, int e) {
    int tid = blockIdx.x * blockDim.x + threadIdx.x;
    int total = e * 16;
    if (tid >= total) return;
    int ei = tid >> 4;       // edge
    int ch = tid & 15;       // float4 chunk within 64 channels
    int r = row[ei];
    int c = col[ei];
    float w = norm[ei];
    float4 v = reinterpret_cast<const float4*>(src)[r * 16 + ch];
    float* d = dst + (size_t)c * OUT_C + ch * 4;
    atomicAdd(d + 0, w * v.x);
    atomicAdd(d + 1, w * v.y);
    atomicAdd(d + 2, w * v.z);
    atomicAdd(d + 3, w * v.w);
}

// ---------------- epilogue: out = sigmoid(out + b) in place ----------------

__global__ void finish_kernel(float* __restrict__ out, const float* __restrict__ b, int n) {
    int i = blockIdx.x * blockDim.x + threadIdx.x;   // over n*16 float4 chunks
    int total = n * (OUT_C / 4);
    if (i >= total) return;
    int ch = i & 15;
    float4 bb = reinterpret_cast<const float4*>(b)[ch];
    float4 v = reinterpret_cast<float4*>(out)[i];
    v.x = 1.0f / (1.0f + __expf(-(v.x + bb.x)));
    v.y = 1.0f / (1.0f + __expf(-(v.y + bb.y)));
    v.z = 1.0f / (1.0f + __expf(-(v.z + bb.z)));
    v.w = 1.0f / (1.0f + __expf(-(v.w + bb.w)));
    reinterpret_cast<float4*>(out)[i] = v;
}

extern "C" void kernel_launch(void* const* d_in, const int* in_sizes, int n_in,
                              void* d_out, int out_size, void* d_ws, size_t ws_size,
                              hipStream_t stream) {
    const float* x = (const float*)d_in[0];
    const int* edge_index = (const int*)d_in[1];   // [2, E] int32 per harness convention
    const float* W = (const float*)d_in[2];
    const float* b = (const float*)d_in[3];
    float* out = (float*)d_out;

    const int N = N_NODES;
    const int E = in_sizes[1] / 2;   // 800000

    const int* row = edge_index;        // source
    const int* col = edge_index + E;    // destination

    // workspace layout (floats): dinv[N] | norm[E] | y0[N*64] | y1[N*64]
    float* dinv = (float*)d_ws;
    float* norm = dinv + N;
    float* y0 = norm + E;
    float* y1 = y0 + (size_t)N * OUT_C;

    const int B = 256;

    // 1) degrees (with self-loop) -> dinv
    deg_init_kernel<<<(N + B - 1) / B, B, 0, stream>>>(dinv, N);
    deg_scatter_kernel<<<(E + B - 1) / B, B, 0, stream>>>(col, dinv, E);
    dinv_kernel<<<(N + B - 1) / B, B, 0, stream>>>(dinv, N);

    // 2) per-edge norm
    norm_kernel<<<(E + B - 1) / B, B, 0, stream>>>(row, col, dinv, norm, E);

    // 3) linear first (propagation commutes with W): y0 = x @ W^T
    linear_kernel<<<(N + 3) / 4, B, 0, stream>>>(x, W, y0, N);

    // 4) hop 1: y1 = D^-1/2 (A+I) D^-1/2 y0
    hop_init_kernel<<<(N * 16 + B - 1) / B, B, 0, stream>>>(y0, y1, dinv, N);
    hop_scatter_kernel<<<(E * 16 + B - 1) / B, B, 0, stream>>>(y0, y1, row, col, norm, E);

    // 5) hop 2: out = D^-1/2 (A+I) D^-1/2 y1   (accumulate directly in d_out)
    hop_init_kernel<<<(N * 16 + B - 1) / B, B, 0, stream>>>(y1, out, dinv, N);
    hop_scatter_kernel<<<(E * 16 + B - 1) / B, B, 0, stream>>>(y1, out, row, col, norm, E);

    // 6) out = sigmoid(out + b)
    finish_kernel<<<(N * 16 + B - 1) / B, B, 0, stream>>>(out, b, N);
}

// Round 2
// 642.214 us; speedup vs baseline: 2.7860x; 2.7860x over previous
//
#include <hip/hip_runtime.h>
#include <hip/hip_bf16.h>
#include <math.h>

#define N_NODES 100000
#define N_EDGES 800000
#define IN_C 96
#define OUT_C 64

// ================= CSR build =================

__global__ void zero_int_kernel(int* __restrict__ p, int n) {
    int i = blockIdx.x * blockDim.x + threadIdx.x;
    if (i < n) p[i] = 0;
}

// in-degree counts (without self-loop)
__global__ void count_kernel(const int* __restrict__ col, int* __restrict__ cnt, int e) {
    int i = blockIdx.x * blockDim.x + threadIdx.x;
    if (i < e) atomicAdd(&cnt[col[i]], 1);
}

// dinv[i] = rsqrt(cnt[i] + 1)   (+1 = self-loop)
__global__ void dinv_kernel(const int* __restrict__ cnt, float* __restrict__ dinv, int n) {
    int i = blockIdx.x * blockDim.x + threadIdx.x;
    if (i < n) dinv[i] = rsqrtf((float)cnt[i] + 1.0f);
}

// pass 1: per-block sums of cnt
__global__ void scan_pass1_kernel(const int* __restrict__ cnt, int* __restrict__ partials, int n) {
    __shared__ int s[256];
    int i = blockIdx.x * 256 + threadIdx.x;
    int v = (i < n) ? cnt[i] : 0;
    s[threadIdx.x] = v;
    __syncthreads();
    for (int off = 128; off > 0; off >>= 1) {
        if (threadIdx.x < off) s[threadIdx.x] += s[threadIdx.x + off];
        __syncthreads();
    }
    if (threadIdx.x == 0) partials[blockIdx.x] = s[0];
}

// pass 2: exclusive scan of partials (single block, nparts <= 512), writes total to row_start[n_nodes]
__global__ void scan_pass2_kernel(int* __restrict__ partials, int* __restrict__ row_start,
                                  int nparts, int n_nodes) {
    __shared__ int s[512];
    int t = threadIdx.x;
    int v = (t < nparts) ? partials[t] : 0;
    s[t] = v;
    __syncthreads();
    for (int off = 1; off < 512; off <<= 1) {
        int tmp = (t >= off) ? s[t - off] : 0;
        __syncthreads();
        s[t] += tmp;
        __syncthreads();
    }
    if (t < nparts) partials[t] = s[t] - v;  // exclusive
    if (t == 511) row_start[n_nodes] = s[511];  // total edge count
}

// pass 3: row_start[i] = partials[block] + exclusive_scan_within_block; cursor = copy
__global__ void scan_pass3_kernel(const int* __restrict__ cnt, const int* __restrict__ partials,
                                  int* __restrict__ row_start, int* __restrict__ cursor, int n) {
    __shared__ int s[256];
    int i = blockIdx.x * 256 + threadIdx.x;
    int t = threadIdx.x;
    int v = (i < n) ? cnt[i] : 0;
    s[t] = v;
    __syncthreads();
    for (int off = 1; off < 256; off <<= 1) {
        int tmp = (t >= off) ? s[t - off] : 0;
        __syncthreads();
        s[t] += tmp;
        __syncthreads();
    }
    if (i < n) {
        int start = partials[blockIdx.x] + s[t] - v;  // exclusive
        row_start[i] = start;
        cursor[i] = start;
    }
}

// bucket-scatter edges into CSR: csr[pos] = {src, w = dinv[src]*dinv[dst]}
__global__ void csr_fill_kernel(const int* __restrict__ row, const int* __restrict__ col,
                                const float* __restrict__ dinv, int* __restrict__ cursor,
                                int2* __restrict__ csr, int e) {
    int i = blockIdx.x * blockDim.x + threadIdx.x;
    if (i >= e) return;
    int r = row[i];
    int c = col[i];
    float w = dinv[r] * dinv[c];
    int pos = atomicAdd(&cursor[c], 1);
    csr[pos] = make_int2(r, __float_as_int(w));
}

// ================= linear: y0 = x @ W^T (no bias) =================

__global__ void linear_kernel(const float* __restrict__ x, const float* __restrict__ W,
                              float* __restrict__ y, int n) {
    __shared__ float Wt[IN_C * OUT_C];   // Wt[c*64 + o] = W[o*96 + c]  (24 KB)
    __shared__ float xs[4][IN_C];

    for (int i = threadIdx.x; i < IN_C * OUT_C; i += 256) {
        int o = i / IN_C;
        int c = i - o * IN_C;
        Wt[c * OUT_C + o] = W[i];
    }
    int node0 = blockIdx.x * 4;
    for (int i = threadIdx.x; i < 4 * IN_C; i += 256) {
        int nl = i / IN_C;
        int c = i - nl * IN_C;
        int node = node0 + nl;
        xs[nl][c] = (node < n) ? x[(size_t)node * IN_C + c] : 0.0f;
    }
    __syncthreads();

    int nl = threadIdx.x >> 6;
    int o = threadIdx.x & 63;
    int node = node0 + nl;
    if (node >= n) return;

    float acc = 0.0f;
#pragma unroll
    for (int c = 0; c < IN_C; ++c) {
        acc += xs[nl][c] * Wt[c * OUT_C + o];
    }
    y[(size_t)node * OUT_C + o] = acc;
}

// ================= gather hop: one wave per node, lane = channel =================
// dst[n][ch] = dinv[n]^2 * src[n][ch] + sum_{e: col==n} w_e * src[row_e][ch]
// FINAL: apply bias + sigmoid.

template <bool FINAL>
__global__ void gather_kernel(const float* __restrict__ src, float* __restrict__ dst,
                              const int* __restrict__ row_start, const int2* __restrict__ csr,
                              const float* __restrict__ dinv, const float* __restrict__ bias,
                              int n) {
    int node = blockIdx.x * (blockDim.x >> 6) + (threadIdx.x >> 6);
    if (node >= n) return;
    int ch = threadIdx.x & 63;

    float s = dinv[node];
    float acc = s * s * src[(size_t)node * OUT_C + ch];

    int beg = row_start[node];
    int end = row_start[node + 1];
    for (int j = beg; j < end; ++j) {
        int2 p = csr[j];                       // wave-uniform 8B broadcast
        float w = __int_as_float(p.y);
        acc += w * src[(size_t)p.x * OUT_C + ch];  // coalesced 256B gather
    }
    if (FINAL) {
        acc += bias[ch];
        acc = 1.0f / (1.0f + __expf(-acc));
    }
    dst[(size_t)node * OUT_C + ch] = acc;
}

// ================= launch =================

static inline size_t align16(size_t x) { return (x + 15) & ~(size_t)15; }

extern "C" void kernel_launch(void* const* d_in, const int* in_sizes, int n_in,
                              void* d_out, int out_size, void* d_ws, size_t ws_size,
                              hipStream_t stream) {
    const float* x = (const float*)d_in[0];
    const int* edge_index = (const int*)d_in[1];
    const float* W = (const float*)d_in[2];
    const float* b = (const float*)d_in[3];
    float* out = (float*)d_out;

    const int N = N_NODES;
    const int E = in_sizes[1] / 2;

    const int* row = edge_index;        // source
    const int* col = edge_index + E;    // destination

    // workspace layout
    char* ws = (char*)d_ws;
    size_t off = 0;
    int* cnt = (int*)(ws + off);        off = align16(off + (size_t)N * 4);
    float* dinv = (float*)(ws + off);   off = align16(off + (size_t)N * 4);
    int* row_start = (int*)(ws + off);  off = align16(off + (size_t)(N + 1) * 4);
    int* cursor = (int*)(ws + off);     off = align16(off + (size_t)N * 4);
    int* partials = (int*)(ws + off);   off = align16(off + 512 * 4);
    int2* csr = (int2*)(ws + off);      off = align16(off + (size_t)E * 8);
    float* y0 = (float*)(ws + off);     off = align16(off + (size_t)N * OUT_C * 4);
    float* y1 = (float*)(ws + off);     off = align16(off + (size_t)N * OUT_C * 4);

    const int B = 256;
    const int nb_n = (N + B - 1) / B;       // 391
    const int nb_e = (E + B - 1) / B;

    // ---- CSR build ----
    zero_int_kernel<<<nb_n, B, 0, stream>>>(cnt, N);
    count_kernel<<<nb_e, B, 0, stream>>>(col, cnt, E);
    dinv_kernel<<<nb_n, B, 0, stream>>>(cnt, dinv, N);
    scan_pass1_kernel<<<nb_n, B, 0, stream>>>(cnt, partials, N);
    scan_pass2_kernel<<<1, 512, 0, stream>>>(partials, row_start, nb_n, N);
    scan_pass3_kernel<<<nb_n, B, 0, stream>>>(cnt, partials, row_start, cursor, N);
    csr_fill_kernel<<<nb_e, B, 0, stream>>>(row, col, dinv, cursor, csr, E);

    // ---- linear first (propagation commutes with W): y0 = x @ W^T ----
    linear_kernel<<<(N + 3) / 4, B, 0, stream>>>(x, W, y0, N);

    // ---- hop 1: y1 = D^-1/2 (A+I) D^-1/2 y0 ----
    gather_kernel<false><<<(N + 3) / 4, B, 0, stream>>>(y0, y1, row_start, csr, dinv, b, N);

    // ---- hop 2 + bias + sigmoid -> out ----
    gather_kernel<true><<<(N + 3) / 4, B, 0, stream>>>(y1, out, row_start, csr, dinv, b, N);
}